// Round 8
// baseline (427.460 us; speedup 1.0000x reference)
//
#include <hip/hip_runtime.h>
#include <stdint.h>
#include <stddef.h>

#define B_ 8
#define N_ 2048
#define C_ 2048
#define D_ 256
#define H_ 256

typedef __bf16 bf16x8 __attribute__((ext_vector_type(8)));
typedef __bf16 bf16x4 __attribute__((ext_vector_type(4)));
typedef float f32x4 __attribute__((ext_vector_type(4)));

#define MFMA16(a, b, c) __builtin_amdgcn_mfma_f32_16x16x32_bf16((a), (b), (c), 0, 0, 0)

// ---------------------------------------------------------------------------
// K0a/K0b: collapse score projections to vectors (unchanged from r7).
// ---------------------------------------------------------------------------
__global__ __launch_bounds__(256) void k0a_partial(
    const float* __restrict__ oma_q_w, const float* __restrict__ oma_kv_w,
    const float* __restrict__ sa_w_w,
    const float* __restrict__ oma_s_w, const float* __restrict__ sa_s_w,
    float* __restrict__ partial)
{
    int d = threadIdx.x;
    int vec = blockIdx.x >> 3, hc = blockIdx.x & 7;
    int h0 = hc * 32;
    const float* Wb; const float* sv;
    if (vec == 0)      { Wb = oma_q_w  + h0 * 256;         sv = oma_s_w + h0; }
    else if (vec == 1) { Wb = oma_kv_w + h0 * 256;         sv = oma_s_w + 256 + h0; }
    else if (vec == 2) { Wb = sa_w_w   + h0 * 256;         sv = sa_s_w + h0; }
    else               { Wb = sa_w_w   + (256 + h0) * 256; sv = sa_s_w + 256 + h0; }
    float a = 0.f;
    #pragma unroll 8
    for (int h = 0; h < 32; ++h) a += Wb[h * 256 + d] * sv[h];
    partial[blockIdx.x * 256 + d] = a;
}

__global__ __launch_bounds__(256) void k0b_reduce(
    const float* __restrict__ partial,
    const float* __restrict__ oma_q_b, const float* __restrict__ oma_kv_b,
    const float* __restrict__ oma_s_w, const float* __restrict__ oma_s_b,
    const float* __restrict__ sa_w_b, const float* __restrict__ sa_s_w,
    const float* __restrict__ sa_s_b,
    float* __restrict__ wq_v, float* __restrict__ wk_v,
    float* __restrict__ wq2_v, float* __restrict__ wk2_v,
    float* __restrict__ sb)
{
    int d = threadIdx.x;
    float a0 = 0.f, a1 = 0.f, a2 = 0.f, a3 = 0.f;
    #pragma unroll
    for (int hc = 0; hc < 8; ++hc) {
        a0 += partial[(0 * 8 + hc) * 256 + d];
        a1 += partial[(1 * 8 + hc) * 256 + d];
        a2 += partial[(2 * 8 + hc) * 256 + d];
        a3 += partial[(3 * 8 + hc) * 256 + d];
    }
    wq_v[d] = a0; wk_v[d] = a1; wq2_v[d] = a2; wk2_v[d] = a3;

    int h = d;
    float p1 = oma_q_b[h] * oma_s_w[h] + oma_kv_b[h] * oma_s_w[256 + h];
    float p2 = sa_w_b[h] * sa_s_w[h] + sa_w_b[256 + h] * sa_s_w[256 + h];
    for (int o = 32; o; o >>= 1) { p1 += __shfl_xor(p1, o); p2 += __shfl_xor(p2, o); }
    __shared__ float redA[4], redB[4];
    int wv = threadIdx.x >> 6;
    if ((threadIdx.x & 63) == 0) { redA[wv] = p1; redB[wv] = p2; }
    __syncthreads();
    if (threadIdx.x == 0) {
        sb[0] = redA[0] + redA[1] + redA[2] + redA[3] + oma_s_b[0];
        sb[1] = redB[0] + redB[1] + redB[2] + redB[3] + sa_s_b[0];
    }
}

// ---------------------------------------------------------------------------
// K1: fold output projections through mix (unchanged from r7).
// ---------------------------------------------------------------------------
__global__ __launch_bounds__(256) void k1_wcat(
    const float* __restrict__ mix_w, const float* __restrict__ mix_b,
    const float* __restrict__ oma_o_w, const float* __restrict__ oma_o_b,
    const float* __restrict__ sa_o_w, const float* __restrict__ sa_o_b,
    __bf16* __restrict__ Wcat, float* __restrict__ b_total)
{
    int d = blockIdx.x, h = threadIdx.x;
    const float* mwr = mix_w + d * 512;
    float w1 = 0.f, w2 = 0.f;
    for (int e = 0; e < 256; ++e) {
        w1 += mwr[e] * oma_o_w[e * 256 + h];
        w2 += mwr[256 + e] * sa_o_w[e * 256 + h];
    }
    Wcat[d * 512 + h] = (__bf16)w1;
    Wcat[d * 512 + 256 + h] = (__bf16)w2;

    float pb = mwr[h] * oma_o_b[h] + mwr[256 + h] * sa_o_b[h];
    for (int o = 32; o; o >>= 1) pb += __shfl_xor(pb, o);
    __shared__ float red[4];
    if ((h & 63) == 0) red[h >> 6] = pb;
    __syncthreads();
    if (h == 0) b_total[d] = mix_b[d] + red[0] + red[1] + red[2] + red[3];
}

// ---------------------------------------------------------------------------
// K2: per-row score scalars + bf16 feature export (unchanged from r7).
// ---------------------------------------------------------------------------
__global__ __launch_bounds__(256) void k2_scores(
    const float* __restrict__ op, const float* __restrict__ mach,
    const float* __restrict__ wq_v, const float* __restrict__ wk_v,
    const float* __restrict__ wq2_v, const float* __restrict__ wk2_v,
    const float* __restrict__ sb,
    float* __restrict__ sqp, float* __restrict__ skv,
    float* __restrict__ sq2p, float* __restrict__ sk2v,
    __bf16* __restrict__ opb, __bf16* __restrict__ machb)
{
    int t = threadIdx.x, lane = t & 63, wv = t >> 6;
    size_t n = (size_t)blockIdx.x * 4 + wv;
    const float4 mf = *(const float4*)(mach + n * 256 + lane * 4);
    const float4 of = *(const float4*)(op + n * 256 + lane * 4);
    const float4 q4 = *(const float4*)(wq_v + lane * 4);
    const float4 k4 = *(const float4*)(wk_v + lane * 4);
    const float4 q24 = *(const float4*)(wq2_v + lane * 4);
    const float4 k24 = *(const float4*)(wk2_v + lane * 4);

    bf16x4 mb4, ob4;
    mb4[0] = (__bf16)mf.x; mb4[1] = (__bf16)mf.y; mb4[2] = (__bf16)mf.z; mb4[3] = (__bf16)mf.w;
    ob4[0] = (__bf16)of.x; ob4[1] = (__bf16)of.y; ob4[2] = (__bf16)of.z; ob4[3] = (__bf16)of.w;
    *(bf16x4*)(machb + n * 256 + lane * 4) = mb4;
    *(bf16x4*)(opb + n * 256 + lane * 4) = ob4;

    float s1 = mf.x * q4.x + mf.y * q4.y + mf.z * q4.z + mf.w * q4.w;
    float s2 = of.x * k4.x + of.y * k4.y + of.z * k4.z + of.w * k4.w;
    float s3 = mf.x * q24.x + mf.y * q24.y + mf.z * q24.z + mf.w * q24.w;
    float s4 = mf.x * k24.x + mf.y * k24.y + mf.z * k24.z + mf.w * k24.w;
    for (int o = 32; o; o >>= 1) {
        s1 += __shfl_xor(s1, o); s2 += __shfl_xor(s2, o);
        s3 += __shfl_xor(s3, o); s4 += __shfl_xor(s4, o);
    }
    if (lane == 0) {
        sqp[n] = s1 + sb[0]; skv[n] = s2;
        sq2p[n] = s3 + sb[1]; sk2v[n] = s4;
    }
}

// ---------------------------------------------------------------------------
// K3: value projections (unchanged from r7; bf16 B-staging).
// ---------------------------------------------------------------------------
__global__ __launch_bounds__(256, 2) void k3_vgemm(
    const __bf16* __restrict__ opb, const __bf16* __restrict__ machb,
    const float* __restrict__ oma_kv_w, const float* __restrict__ sa_w_w,
    __bf16* __restrict__ vt)
{
    __shared__ __attribute__((aligned(16))) __bf16 As[64][72];
    __shared__ __attribute__((aligned(16))) __bf16 Bs[64][72];
    int t = threadIdx.x;
    int bid = blockIdx.x;
    int which = bid >> 10;
    int r = bid & 1023;
    int b = r >> 7;
    int ht = (r >> 5) & 3;
    int ct = r & 31;

    const float* Aglob = (which ? (sa_w_w + 512 * 256) : (oma_kv_w + 256 * 256)) + ht * 64 * 256;
    const __bf16* Bglob = (which ? machb : opb) + ((size_t)b * N_ + ct * 64) * 256;

    int lane = t & 63, wv = t >> 6;
    int l15 = lane & 15, qo = (lane >> 4) * 8;
    int rr = t >> 4;
    int dd = (t & 15) * 4;

    f32x4 acc[4] = {};

    for (int d0 = 0; d0 < 256; d0 += 64) {
        #pragma unroll
        for (int p = 0; p < 4; ++p) {
            float4 av = *(const float4*)(Aglob + (size_t)(p * 16 + rr) * 256 + d0 + dd);
            bf16x4 a4;
            a4[0] = (__bf16)av.x; a4[1] = (__bf16)av.y; a4[2] = (__bf16)av.z; a4[3] = (__bf16)av.w;
            *(bf16x4*)&As[p * 16 + rr][dd] = a4;
            bf16x4 b4 = *(const bf16x4*)(Bglob + (size_t)(p * 16 + rr) * 256 + d0 + dd);
            *(bf16x4*)&Bs[p * 16 + rr][dd] = b4;
        }
        __syncthreads();
        #pragma unroll
        for (int kb = 0; kb < 2; ++kb) {
            bf16x8 bfr = *(const bf16x8*)&Bs[16 * wv + l15][kb * 32 + qo];
            #pragma unroll
            for (int rt = 0; rt < 4; ++rt) {
                bf16x8 afr = *(const bf16x8*)&As[16 * rt + l15][kb * 32 + qo];
                acc[rt] = MFMA16(afr, bfr, acc[rt]);
            }
        }
        __syncthreads();
    }
    #pragma unroll
    for (int rt = 0; rt < 4; ++rt)
        #pragma unroll
        for (int j = 0; j < 4; ++j)
            As[16 * rt + (lane >> 4) * 4 + j][16 * wv + l15] = (__bf16)acc[rt][j];
    __syncthreads();
    int hh = t >> 2, cb = (t & 3) * 16;
    __bf16* orow = vt + (((size_t)(which * 8 + b)) * 256 + ht * 64 + hh) * 2048 + ct * 64 + cb;
    *(bf16x8*)(orow) = *(const bf16x8*)&As[hh][cb];
    *(bf16x8*)(orow + 8) = *(const bf16x8*)&As[hh][cb + 8];
}

// ---------------------------------------------------------------------------
// K4 v6: r0 skeleton (LDS-staged V, same tiling/epilogue) with the per-chunk
// HBM-latency tail removed:
//   - in-loop barriers are raw lgkmcnt(0)+s_barrier (NO vmcnt drain; the
//     compiler's counted vmcnt waits at each consumer do the exact waiting)
//   - mask+sk prefetch depth-2 (two named reg sets, ping-pong, body
//     unrolled x2 so all indices are compile-time); V stays depth-1 via LDS
//   - per-chunk issue order: V(i+1) then mask(i+2) -> waiting on V never
//     drains the youngest mask loads (vmcnt is in-order)
// ---------------------------------------------------------------------------
__global__ __launch_bounds__(256, 2) void k4_attn(
    const float* __restrict__ tmask, const float* __restrict__ smask,
    const float* __restrict__ sqp, const float* __restrict__ skv,
    const float* __restrict__ sq2p, const float* __restrict__ sk2v,
    const __bf16* __restrict__ vt,
    __bf16* __restrict__ wfcat)
{
    __shared__ __attribute__((aligned(16))) __bf16 eA[64][72];
    __shared__ __attribute__((aligned(16))) __bf16 vB[256][72];
    __shared__ float rowsum[64];

    int t = threadIdx.x;
    int bid = blockIdx.x;
    int which = bid >> 8;
    int r = bid & 255;
    int b = r >> 5;
    int m0 = (r & 31) * 64;

    const float* mask = (which ? smask : tmask) + ((size_t)b * N_ + m0) * C_;
    const float* sqrow = (which ? sq2p : sqp) + b * N_ + m0;
    const float* skrow = (which ? sk2v : skv) + b * N_;
    const __bf16* vbase = vt + ((size_t)(which * 8 + b)) * 256 * 2048;

    int lane = t & 63, wv = t >> 6;
    int l15 = lane & 15, qo = (lane >> 4) * 8;
    int mrow = t >> 2;          // 0..63 : my e-row
    int cqb = (t & 3) * 16;     // my 16-col slice within the 64-chunk
    int vh = t >> 3;            // 0..31 : v staging row
    int vc = (t & 7) * 8;

    float sqv = sqrow[mrow];
    float psum = 0.f;
    f32x4 acc[4][4] = {};

    bf16x8 vv[8];
    float mkA[16], skA[16], mkB[16], skB[16];

    auto load_v = [&](int c0) {
        #pragma unroll
        for (int p = 0; p < 8; ++p)
            vv[p] = *(const bf16x8*)(vbase + (size_t)(p * 32 + vh) * 2048 + c0 + vc);
    };
    auto load_ms = [&](float* mk, float* skc, int c0) {
        #pragma unroll
        for (int i = 0; i < 4; ++i) {
            float4 m4 = *(const float4*)(mask + (size_t)mrow * C_ + c0 + cqb + i * 4);
            float4 s4 = *(const float4*)(skrow + c0 + cqb + i * 4);
            mk[4 * i + 0] = m4.x; mk[4 * i + 1] = m4.y; mk[4 * i + 2] = m4.z; mk[4 * i + 3] = m4.w;
            skc[4 * i + 0] = s4.x; skc[4 * i + 1] = s4.y; skc[4 * i + 2] = s4.z; skc[4 * i + 3] = s4.w;
        }
    };
    auto stage_v = [&]() {
        #pragma unroll
        for (int p = 0; p < 8; ++p)
            *(bf16x8*)&vB[p * 32 + vh][vc] = vv[p];
    };
    auto compute_e = [&](const float* mk, const float* skc) {
        bf16x8 e0, e1;
        #pragma unroll
        for (int i = 0; i < 16; ++i) {
            float s = sqv + skc[i];
            s = s > 0.f ? s : 0.01f * s;
            float e = __expf(s * mk[i]);
            psum += e;
            if (i < 8) e0[i] = (__bf16)e; else e1[i - 8] = (__bf16)e;
        }
        *(bf16x8*)&eA[mrow][cqb] = e0;
        *(bf16x8*)&eA[mrow][cqb + 8] = e1;
    };
    auto do_mfma = [&]() {
        #pragma unroll
        for (int kb = 0; kb < 2; ++kb) {
            bf16x8 afr[4];
            #pragma unroll
            for (int rt = 0; rt < 4; ++rt)
                afr[rt] = *(const bf16x8*)&eA[16 * rt + l15][kb * 32 + qo];
            #pragma unroll
            for (int ctile = 0; ctile < 4; ++ctile) {
                bf16x8 bfr = *(const bf16x8*)&vB[64 * wv + 16 * ctile + l15][kb * 32 + qo];
                #pragma unroll
                for (int rt = 0; rt < 4; ++rt)
                    acc[rt][ctile] = MFMA16(afr[rt], bfr, acc[rt][ctile]);
            }
        }
    };
    auto lgkm_barrier = []() {
        asm volatile("s_waitcnt lgkmcnt(0)" ::: "memory");
        __builtin_amdgcn_s_barrier();
    };

    // prologue: V(0) first, then mask(0), mask(1) (issue order matters)
    load_v(0);
    load_ms(mkA, skA, 0);
    load_ms(mkB, skB, 64);

    #pragma unroll 1
    for (int c0 = 0; c0 < C_; c0 += 128) {
        // ---- even chunk i = c0 : consumes vv=V(i), mkA=mask(i) ----
        stage_v();                              // counted-vmcnt wait drains V(i) only
        compute_e(mkA, skA);                    // drains mask(i) (older than V(i+1))
        lgkm_barrier();                         // stage visible; no vmem drain
        load_v((c0 + 64) & (C_ - 1));           // issue V(i+1)
        load_ms(mkA, skA, (c0 + 128) & (C_ - 1)); // issue mask(i+2)
        do_mfma();
        lgkm_barrier();                         // all LDS reads done; loads fly on
        // ---- odd chunk i+1 : consumes vv=V(i+1), mkB=mask(i+1) ----
        stage_v();
        compute_e(mkB, skB);
        lgkm_barrier();
        load_v((c0 + 128) & (C_ - 1));          // issue V(i+2)
        load_ms(mkB, skB, (c0 + 192) & (C_ - 1)); // issue mask(i+3)
        do_mfma();
        lgkm_barrier();
    }

    // rowsum: 4 threads per row hold disjoint column partials
    float rs = psum;
    rs += __shfl_xor(rs, 1);
    rs += __shfl_xor(rs, 2);
    if ((t & 3) == 0) rowsum[mrow] = rs;
    __syncthreads();

    // normalize, pack [64][256] through LDS (reuse vB), coalesced store
    __bf16* obuf = &vB[0][0];   // treated as [64][264]
    #pragma unroll
    for (int rt = 0; rt < 4; ++rt) {
        #pragma unroll
        for (int j = 0; j < 4; ++j) {
            int m = 16 * rt + (lane >> 4) * 4 + j;
            float inv = __builtin_amdgcn_rcpf(rowsum[m]);
            #pragma unroll
            for (int ctile = 0; ctile < 4; ++ctile)
                obuf[m * 264 + 64 * wv + 16 * ctile + l15] = (__bf16)(acc[rt][ctile][j] * inv);
        }
    }
    __syncthreads();
    int m = t >> 2, cb = (t & 3) * 64;
    __bf16* wrow = wfcat + ((size_t)(b * N_ + m0 + m)) * 512 + which * 256 + cb;
    #pragma unroll
    for (int k = 0; k < 8; ++k)
        *(bf16x8*)(wrow + k * 8) = *(const bf16x8*)&obuf[m * 264 + cb + k * 8];
}

// ---------------------------------------------------------------------------
// K5: out[n][d] = wfcat[n][:512] . Wcat[d][:512] + b_total[d] (unchanged).
// ---------------------------------------------------------------------------
__global__ __launch_bounds__(256, 2) void k5_out(
    const __bf16* __restrict__ wfcat, const __bf16* __restrict__ Wcat,
    const float* __restrict__ b_total, float* __restrict__ out)
{
    __shared__ __attribute__((aligned(16))) __bf16 As[32][72];
    __shared__ __attribute__((aligned(16))) __bf16 Bs[256][72];
    __shared__ float bias[256];
    int t = threadIdx.x;
    int n0 = blockIdx.x * 32;
    int lane = t & 63, wv = t >> 6, l15 = lane & 15, qo = (lane >> 4) * 8;
    bias[t] = b_total[t];
    int ar = t >> 3;
    int ac = (t & 7) * 8;
    f32x4 acc[2][4] = {};

    for (int k0 = 0; k0 < 512; k0 += 64) {
        *(bf16x8*)&As[ar][ac] =
            *(const bf16x8*)(wfcat + (size_t)(n0 + ar) * 512 + k0 + ac);
        #pragma unroll
        for (int p = 0; p < 8; ++p)
            *(bf16x8*)&Bs[p * 32 + ar][ac] =
                *(const bf16x8*)(Wcat + (size_t)(p * 32 + ar) * 512 + k0 + ac);
        __syncthreads();
        #pragma unroll
        for (int kb = 0; kb < 2; ++kb) {
            bf16x8 afr[2];
            #pragma unroll
            for (int rt = 0; rt < 2; ++rt)
                afr[rt] = *(const bf16x8*)&As[16 * rt + l15][kb * 32 + qo];
            #pragma unroll
            for (int ct = 0; ct < 4; ++ct) {
                bf16x8 bfr = *(const bf16x8*)&Bs[64 * wv + 16 * ct + l15][kb * 32 + qo];
                #pragma unroll
                for (int rt = 0; rt < 2; ++rt)
                    acc[rt][ct] = MFMA16(afr[rt], bfr, acc[rt][ct]);
            }
        }
        __syncthreads();
    }
    #pragma unroll
    for (int rt = 0; rt < 2; ++rt) {
        #pragma unroll
        for (int ct = 0; ct < 4; ++ct) {
            int d = 64 * wv + 16 * ct + l15;
            float bv = bias[d];
            #pragma unroll
            for (int j = 0; j < 4; ++j) {
                int m = 16 * rt + (lane >> 4) * 4 + j;
                out[(size_t)(n0 + m) * 256 + d] = acc[rt][ct][j] + bv;
            }
        }
    }
}

// ---------------------------------------------------------------------------
extern "C" void kernel_launch(void* const* d_in, const int* in_sizes, int n_in,
                              void* d_out, int out_size, void* d_ws, size_t ws_size,
                              hipStream_t stream)
{
    const float* op_feat  = (const float*)d_in[0];
    const float* mach_feat= (const float*)d_in[1];
    const float* tmask    = (const float*)d_in[2];
    const float* smask    = (const float*)d_in[3];
    const float* oma_q_w  = (const float*)d_in[4];
    const float* oma_q_b  = (const float*)d_in[5];
    const float* oma_kv_w = (const float*)d_in[6];
    const float* oma_kv_b = (const float*)d_in[7];
    const float* oma_s_w  = (const float*)d_in[8];
    const float* oma_s_b  = (const float*)d_in[9];
    const float* oma_o_w  = (const float*)d_in[10];
    const float* oma_o_b  = (const float*)d_in[11];
    const float* sa_w_w   = (const float*)d_in[12];
    const float* sa_w_b   = (const float*)d_in[13];
    const float* sa_s_w   = (const float*)d_in[14];
    const float* sa_s_b   = (const float*)d_in[15];
    const float* sa_o_w   = (const float*)d_in[16];
    const float* sa_o_b   = (const float*)d_in[17];
    const float* mix_w    = (const float*)d_in[18];
    const float* mix_b    = (const float*)d_in[19];

    char* ws = (char*)d_ws;
    float* wq_v   = (float*)(ws + 0);
    float* wk_v   = (float*)(ws + 1024);
    float* wq2_v  = (float*)(ws + 2048);
    float* wk2_v  = (float*)(ws + 3072);
    float* sb     = (float*)(ws + 4096);
    float* btot   = (float*)(ws + 4352);
    float* sqp    = (float*)(ws + 8192);
    float* skv    = (float*)(ws + 73728);
    float* sq2p   = (float*)(ws + 139264);
    float* sk2v   = (float*)(ws + 204800);
    __bf16* Wcat  = (__bf16*)(ws + 270336);    //  256 KB
    __bf16* vt    = (__bf16*)(ws + 532480);    //   16 MB : [2][8][256][2048]
    __bf16* wfcat = (__bf16*)(ws + 17309696);  //   16 MB : [16384][512]
    float* outp   = (float*)d_out;

    float* partial = (float*)(ws + 532480);    // 32 KB, overwritten by k3 later
    __bf16* opb   = (__bf16*)(ws + 17309696);            // 8 MB (dead until k4)
    __bf16* machb = (__bf16*)(ws + 17309696 + 8388608);  // 8 MB (dead until k4)

    k0a_partial<<<32, 256, 0, stream>>>(oma_q_w, oma_kv_w, sa_w_w,
                                        oma_s_w, sa_s_w, partial);
    k0b_reduce<<<1, 256, 0, stream>>>(partial, oma_q_b, oma_kv_b, oma_s_w, oma_s_b,
                                      sa_w_b, sa_s_w, sa_s_b,
                                      wq_v, wk_v, wq2_v, wk2_v, sb);
    k1_wcat<<<256, 256, 0, stream>>>(mix_w, mix_b, oma_o_w, oma_o_b,
                                     sa_o_w, sa_o_b, Wcat, btot);
    k2_scores<<<4096, 256, 0, stream>>>(op_feat, mach_feat, wq_v, wk_v, wq2_v, wk2_v,
                                        sb, sqp, skv, sq2p, sk2v, opb, machb);
    k3_vgemm<<<2048, 256, 0, stream>>>(opb, machb, oma_kv_w, sa_w_w, vt);
    k4_attn<<<512, 256, 0, stream>>>(tmask, smask, sqp, skv, sq2p, sk2v, vt, wfcat);
    k5_out<<<512, 256, 0, stream>>>(wfcat, Wcat, btot, outp);
}

// Round 9
// 407.501 us; speedup vs baseline: 1.0490x; 1.0490x over previous
//
#include <hip/hip_runtime.h>
#include <stdint.h>
#include <stddef.h>

#define B_ 8
#define N_ 2048
#define C_ 2048
#define D_ 256
#define H_ 256

typedef __bf16 bf16x8 __attribute__((ext_vector_type(8)));
typedef __bf16 bf16x4 __attribute__((ext_vector_type(4)));
typedef float f32x4 __attribute__((ext_vector_type(4)));

#define MFMA16(a, b, c) __builtin_amdgcn_mfma_f32_16x16x32_bf16((a), (b), (c), 0, 0, 0)

// ---------------------------------------------------------------------------
// K0a/K0b: collapse score projections to vectors (unchanged).
// ---------------------------------------------------------------------------
__global__ __launch_bounds__(256) void k0a_partial(
    const float* __restrict__ oma_q_w, const float* __restrict__ oma_kv_w,
    const float* __restrict__ sa_w_w,
    const float* __restrict__ oma_s_w, const float* __restrict__ sa_s_w,
    float* __restrict__ partial)
{
    int d = threadIdx.x;
    int vec = blockIdx.x >> 3, hc = blockIdx.x & 7;
    int h0 = hc * 32;
    const float* Wb; const float* sv;
    if (vec == 0)      { Wb = oma_q_w  + h0 * 256;         sv = oma_s_w + h0; }
    else if (vec == 1) { Wb = oma_kv_w + h0 * 256;         sv = oma_s_w + 256 + h0; }
    else if (vec == 2) { Wb = sa_w_w   + h0 * 256;         sv = sa_s_w + h0; }
    else               { Wb = sa_w_w   + (256 + h0) * 256; sv = sa_s_w + 256 + h0; }
    float a = 0.f;
    #pragma unroll 8
    for (int h = 0; h < 32; ++h) a += Wb[h * 256 + d] * sv[h];
    partial[blockIdx.x * 256 + d] = a;
}

__global__ __launch_bounds__(256) void k0b_reduce(
    const float* __restrict__ partial,
    const float* __restrict__ oma_q_b, const float* __restrict__ oma_kv_b,
    const float* __restrict__ oma_s_w, const float* __restrict__ oma_s_b,
    const float* __restrict__ sa_w_b, const float* __restrict__ sa_s_w,
    const float* __restrict__ sa_s_b,
    float* __restrict__ wq_v, float* __restrict__ wk_v,
    float* __restrict__ wq2_v, float* __restrict__ wk2_v,
    float* __restrict__ sb)
{
    int d = threadIdx.x;
    float a0 = 0.f, a1 = 0.f, a2 = 0.f, a3 = 0.f;
    #pragma unroll
    for (int hc = 0; hc < 8; ++hc) {
        a0 += partial[(0 * 8 + hc) * 256 + d];
        a1 += partial[(1 * 8 + hc) * 256 + d];
        a2 += partial[(2 * 8 + hc) * 256 + d];
        a3 += partial[(3 * 8 + hc) * 256 + d];
    }
    wq_v[d] = a0; wk_v[d] = a1; wq2_v[d] = a2; wk2_v[d] = a3;

    int h = d;
    float p1 = oma_q_b[h] * oma_s_w[h] + oma_kv_b[h] * oma_s_w[256 + h];
    float p2 = sa_w_b[h] * sa_s_w[h] + sa_w_b[256 + h] * sa_s_w[256 + h];
    for (int o = 32; o; o >>= 1) { p1 += __shfl_xor(p1, o); p2 += __shfl_xor(p2, o); }
    __shared__ float redA[4], redB[4];
    int wv = threadIdx.x >> 6;
    if ((threadIdx.x & 63) == 0) { redA[wv] = p1; redB[wv] = p2; }
    __syncthreads();
    if (threadIdx.x == 0) {
        sb[0] = redA[0] + redA[1] + redA[2] + redA[3] + oma_s_b[0];
        sb[1] = redB[0] + redB[1] + redB[2] + redB[3] + sa_s_b[0];
    }
}

// ---------------------------------------------------------------------------
// K1: fold output projections through mix. NEW: w1/w2 halves split across 2
// blocks (grid 512 -> 2 blocks/CU, per-block serial chain halved, traffic
// unchanged). Bias reduction stays in the half==0 block.
// ---------------------------------------------------------------------------
__global__ __launch_bounds__(256) void k1_wcat(
    const float* __restrict__ mix_w, const float* __restrict__ mix_b,
    const float* __restrict__ oma_o_w, const float* __restrict__ oma_o_b,
    const float* __restrict__ sa_o_w, const float* __restrict__ sa_o_b,
    __bf16* __restrict__ Wcat, float* __restrict__ b_total)
{
    int bid = blockIdx.x;
    int d = bid >> 1, half = bid & 1;
    int h = threadIdx.x;
    const float* mwr = mix_w + d * 512 + half * 256;
    const float* O = half ? sa_o_w : oma_o_w;
    float w = 0.f;
    for (int e = 0; e < 256; ++e)
        w += mwr[e] * O[e * 256 + h];
    Wcat[d * 512 + half * 256 + h] = (__bf16)w;

    if (half == 0) {
        const float* m2 = mix_w + d * 512;
        float pb = m2[h] * oma_o_b[h] + m2[256 + h] * sa_o_b[h];
        for (int o = 32; o; o >>= 1) pb += __shfl_xor(pb, o);
        __shared__ float red[4];
        if ((h & 63) == 0) red[h >> 6] = pb;
        __syncthreads();
        if (h == 0) b_total[d] = mix_b[d] + red[0] + red[1] + red[2] + red[3];
    }
}

// ---------------------------------------------------------------------------
// K2: per-row score scalars + bf16 feature export (unchanged from r7).
// ---------------------------------------------------------------------------
__global__ __launch_bounds__(256) void k2_scores(
    const float* __restrict__ op, const float* __restrict__ mach,
    const float* __restrict__ wq_v, const float* __restrict__ wk_v,
    const float* __restrict__ wq2_v, const float* __restrict__ wk2_v,
    const float* __restrict__ sb,
    float* __restrict__ sqp, float* __restrict__ skv,
    float* __restrict__ sq2p, float* __restrict__ sk2v,
    __bf16* __restrict__ opb, __bf16* __restrict__ machb)
{
    int t = threadIdx.x, lane = t & 63, wv = t >> 6;
    size_t n = (size_t)blockIdx.x * 4 + wv;
    const float4 mf = *(const float4*)(mach + n * 256 + lane * 4);
    const float4 of = *(const float4*)(op + n * 256 + lane * 4);
    const float4 q4 = *(const float4*)(wq_v + lane * 4);
    const float4 k4 = *(const float4*)(wk_v + lane * 4);
    const float4 q24 = *(const float4*)(wq2_v + lane * 4);
    const float4 k24 = *(const float4*)(wk2_v + lane * 4);

    bf16x4 mb4, ob4;
    mb4[0] = (__bf16)mf.x; mb4[1] = (__bf16)mf.y; mb4[2] = (__bf16)mf.z; mb4[3] = (__bf16)mf.w;
    ob4[0] = (__bf16)of.x; ob4[1] = (__bf16)of.y; ob4[2] = (__bf16)of.z; ob4[3] = (__bf16)of.w;
    *(bf16x4*)(machb + n * 256 + lane * 4) = mb4;
    *(bf16x4*)(opb + n * 256 + lane * 4) = ob4;

    float s1 = mf.x * q4.x + mf.y * q4.y + mf.z * q4.z + mf.w * q4.w;
    float s2 = of.x * k4.x + of.y * k4.y + of.z * k4.z + of.w * k4.w;
    float s3 = mf.x * q24.x + mf.y * q24.y + mf.z * q24.z + mf.w * q24.w;
    float s4 = mf.x * k24.x + mf.y * k24.y + mf.z * k24.z + mf.w * k24.w;
    for (int o = 32; o; o >>= 1) {
        s1 += __shfl_xor(s1, o); s2 += __shfl_xor(s2, o);
        s3 += __shfl_xor(s3, o); s4 += __shfl_xor(s4, o);
    }
    if (lane == 0) {
        sqp[n] = s1 + sb[0]; skv[n] = s2;
        sq2p[n] = s3 + sb[1]; sk2v[n] = s4;
    }
}

// ---------------------------------------------------------------------------
// K3: value projections (unchanged from r7; bf16 B-staging).
// ---------------------------------------------------------------------------
__global__ __launch_bounds__(256, 2) void k3_vgemm(
    const __bf16* __restrict__ opb, const __bf16* __restrict__ machb,
    const float* __restrict__ oma_kv_w, const float* __restrict__ sa_w_w,
    __bf16* __restrict__ vt)
{
    __shared__ __attribute__((aligned(16))) __bf16 As[64][72];
    __shared__ __attribute__((aligned(16))) __bf16 Bs[64][72];
    int t = threadIdx.x;
    int bid = blockIdx.x;
    int which = bid >> 10;
    int r = bid & 1023;
    int b = r >> 7;
    int ht = (r >> 5) & 3;
    int ct = r & 31;

    const float* Aglob = (which ? (sa_w_w + 512 * 256) : (oma_kv_w + 256 * 256)) + ht * 64 * 256;
    const __bf16* Bglob = (which ? machb : opb) + ((size_t)b * N_ + ct * 64) * 256;

    int lane = t & 63, wv = t >> 6;
    int l15 = lane & 15, qo = (lane >> 4) * 8;
    int rr = t >> 4;
    int dd = (t & 15) * 4;

    f32x4 acc[4] = {};

    for (int d0 = 0; d0 < 256; d0 += 64) {
        #pragma unroll
        for (int p = 0; p < 4; ++p) {
            float4 av = *(const float4*)(Aglob + (size_t)(p * 16 + rr) * 256 + d0 + dd);
            bf16x4 a4;
            a4[0] = (__bf16)av.x; a4[1] = (__bf16)av.y; a4[2] = (__bf16)av.z; a4[3] = (__bf16)av.w;
            *(bf16x4*)&As[p * 16 + rr][dd] = a4;
            bf16x4 b4 = *(const bf16x4*)(Bglob + (size_t)(p * 16 + rr) * 256 + d0 + dd);
            *(bf16x4*)&Bs[p * 16 + rr][dd] = b4;
        }
        __syncthreads();
        #pragma unroll
        for (int kb = 0; kb < 2; ++kb) {
            bf16x8 bfr = *(const bf16x8*)&Bs[16 * wv + l15][kb * 32 + qo];
            #pragma unroll
            for (int rt = 0; rt < 4; ++rt) {
                bf16x8 afr = *(const bf16x8*)&As[16 * rt + l15][kb * 32 + qo];
                acc[rt] = MFMA16(afr, bfr, acc[rt]);
            }
        }
        __syncthreads();
    }
    #pragma unroll
    for (int rt = 0; rt < 4; ++rt)
        #pragma unroll
        for (int j = 0; j < 4; ++j)
            As[16 * rt + (lane >> 4) * 4 + j][16 * wv + l15] = (__bf16)acc[rt][j];
    __syncthreads();
    int hh = t >> 2, cb = (t & 3) * 16;
    __bf16* orow = vt + (((size_t)(which * 8 + b)) * 256 + ht * 64 + hh) * 2048 + ct * 64 + cb;
    *(bf16x8*)(orow) = *(const bf16x8*)&As[hh][cb];
    *(bf16x8*)(orow + 8) = *(const bf16x8*)&As[hh][cb + 8];
}

// ---------------------------------------------------------------------------
// K4: fused masked-softmax attention — EXACT round-0 version, FROZEN.
// (five structural redesigns r1-r4,r8 all failed to beat it; 110-126us
// depending on run-to-run chip speed.)
// ---------------------------------------------------------------------------
__global__ __launch_bounds__(256, 2) void k4_attn(
    const float* __restrict__ tmask, const float* __restrict__ smask,
    const float* __restrict__ sqp, const float* __restrict__ skv,
    const float* __restrict__ sq2p, const float* __restrict__ sk2v,
    const __bf16* __restrict__ vt,
    __bf16* __restrict__ wfcat)
{
    __shared__ __attribute__((aligned(16))) __bf16 eA[64][72];
    __shared__ __attribute__((aligned(16))) __bf16 vB[256][72];
    __shared__ float rowsum[64];

    int t = threadIdx.x;
    int bid = blockIdx.x;
    int which = bid >> 8;
    int r = bid & 255;
    int b = r >> 5;
    int m0 = (r & 31) * 64;

    const float* mask = (which ? smask : tmask) + ((size_t)b * N_ + m0) * C_;
    const float* sqrow = (which ? sq2p : sqp) + b * N_ + m0;
    const float* skrow = (which ? sk2v : skv) + b * N_;
    const __bf16* vbase = vt + ((size_t)(which * 8 + b)) * 256 * 2048;

    int lane = t & 63, wv = t >> 6;
    int l15 = lane & 15, qo = (lane >> 4) * 8;
    int mrow = t >> 2;          // 0..63 : my e-row
    int cqb = (t & 3) * 16;     // my 16-col slice within the 64-chunk
    int vh = t >> 3;            // 0..31 : v staging row
    int vc = (t & 7) * 8;

    float sqv = sqrow[mrow];
    float psum = 0.f;
    f32x4 acc[4][4] = {};

    bf16x8 vv[8];
    float mk[16], skc[16];

    auto load_tiles = [&](int c0) {
        #pragma unroll
        for (int p = 0; p < 8; ++p)
            vv[p] = *(const bf16x8*)(vbase + (size_t)(p * 32 + vh) * 2048 + c0 + vc);
        #pragma unroll
        for (int i = 0; i < 4; ++i) {
            float4 m4 = *(const float4*)(mask + (size_t)mrow * C_ + c0 + cqb + i * 4);
            float4 s4 = *(const float4*)(skrow + c0 + cqb + i * 4);
            mk[4 * i + 0] = m4.x; mk[4 * i + 1] = m4.y; mk[4 * i + 2] = m4.z; mk[4 * i + 3] = m4.w;
            skc[4 * i + 0] = s4.x; skc[4 * i + 1] = s4.y; skc[4 * i + 2] = s4.z; skc[4 * i + 3] = s4.w;
        }
    };
    load_tiles(0);

    for (int c0 = 0; c0 < C_; c0 += 64) {
        // stage v tile from prefetched regs
        #pragma unroll
        for (int p = 0; p < 8; ++p)
            *(bf16x8*)&vB[p * 32 + vh][vc] = vv[p];
        // e tile (fp32 math, bf16 store)
        bf16x8 e0, e1;
        #pragma unroll
        for (int i = 0; i < 16; ++i) {
            float s = sqv + skc[i];
            s = s > 0.f ? s : 0.01f * s;
            float e = __expf(s * mk[i]);
            psum += e;
            if (i < 8) e0[i] = (__bf16)e; else e1[i - 8] = (__bf16)e;
        }
        *(bf16x8*)&eA[mrow][cqb] = e0;
        *(bf16x8*)&eA[mrow][cqb + 8] = e1;
        __syncthreads();
        // prefetch next chunk's globals; latency overlaps the MFMA phase
        int cn = c0 + 64; if (cn >= C_) cn = 0;
        load_tiles(cn);
        #pragma unroll
        for (int kb = 0; kb < 2; ++kb) {
            bf16x8 afr[4];
            #pragma unroll
            for (int rt = 0; rt < 4; ++rt)
                afr[rt] = *(const bf16x8*)&eA[16 * rt + l15][kb * 32 + qo];
            #pragma unroll
            for (int ctile = 0; ctile < 4; ++ctile) {
                bf16x8 bfr = *(const bf16x8*)&vB[64 * wv + 16 * ctile + l15][kb * 32 + qo];
                #pragma unroll
                for (int rt = 0; rt < 4; ++rt)
                    acc[rt][ctile] = MFMA16(afr[rt], bfr, acc[rt][ctile]);
            }
        }
        __syncthreads();
    }

    // rowsum: 4 threads per row hold disjoint column partials
    float rs = psum;
    rs += __shfl_xor(rs, 1);
    rs += __shfl_xor(rs, 2);
    if ((t & 3) == 0) rowsum[mrow] = rs;
    __syncthreads();

    // normalize, pack [64][256] through LDS (reuse vB), coalesced store
    __bf16* obuf = &vB[0][0];   // treated as [64][264]
    #pragma unroll
    for (int rt = 0; rt < 4; ++rt) {
        #pragma unroll
        for (int j = 0; j < 4; ++j) {
            int m = 16 * rt + (lane >> 4) * 4 + j;
            float inv = __builtin_amdgcn_rcpf(rowsum[m]);
            #pragma unroll
            for (int ctile = 0; ctile < 4; ++ctile)
                obuf[m * 264 + 64 * wv + 16 * ctile + l15] = (__bf16)(acc[rt][ctile][j] * inv);
        }
    }
    __syncthreads();
    int m = t >> 2, cb = (t & 3) * 64;
    __bf16* wrow = wfcat + ((size_t)(b * N_ + m0 + m)) * 512 + which * 256 + cb;
    #pragma unroll
    for (int k = 0; k < 8; ++k)
        *(bf16x8*)(wrow + k * 8) = *(const bf16x8*)&obuf[m * 264 + cb + k * 8];
}

// ---------------------------------------------------------------------------
// K5: out[n][d] = wfcat[n][:512] . Wcat[d][:512] + b_total[d]
// NEW: 16-row tiles, grid 1024, launch_bounds(256,4) -> 4 blocks/CU
// (LDS 40.2KB x 4 = 157KB fits). Per-block serial chain halved; Wcat stays
// L2-hot so the doubled re-read is free.
// ---------------------------------------------------------------------------
__global__ __launch_bounds__(256, 4) void k5_out(
    const __bf16* __restrict__ wfcat, const __bf16* __restrict__ Wcat,
    const float* __restrict__ b_total, float* __restrict__ out)
{
    __shared__ __attribute__((aligned(16))) __bf16 As[16][72];
    __shared__ __attribute__((aligned(16))) __bf16 Bs[256][72];
    __shared__ float bias[256];
    int t = threadIdx.x;
    int n0 = blockIdx.x * 16;
    int lane = t & 63, wv = t >> 6, l15 = lane & 15, qo = (lane >> 4) * 8;
    bias[t] = b_total[t];
    int ar = t >> 4;           // 0..15
    int ac = (t & 15) * 4;     // 0..60
    int br = t >> 3;           // 0..31
    int bc = (t & 7) * 8;
    f32x4 acc[4] = {};

    for (int k0 = 0; k0 < 512; k0 += 64) {
        *(bf16x4*)&As[ar][ac] =
            *(const bf16x4*)(wfcat + (size_t)(n0 + ar) * 512 + k0 + ac);
        #pragma unroll
        for (int p = 0; p < 8; ++p)
            *(bf16x8*)&Bs[p * 32 + br][bc] =
                *(const bf16x8*)(Wcat + (size_t)(p * 32 + br) * 512 + k0 + bc);
        __syncthreads();
        #pragma unroll
        for (int kb = 0; kb < 2; ++kb) {
            bf16x8 afr = *(const bf16x8*)&As[l15][kb * 32 + qo];
            #pragma unroll
            for (int ct = 0; ct < 4; ++ct) {
                bf16x8 bfr = *(const bf16x8*)&Bs[64 * wv + 16 * ct + l15][kb * 32 + qo];
                acc[ct] = MFMA16(afr, bfr, acc[ct]);
            }
        }
        __syncthreads();
    }
    #pragma unroll
    for (int ct = 0; ct < 4; ++ct) {
        int d = 64 * wv + 16 * ct + l15;
        float bv = bias[d];
        #pragma unroll
        for (int j = 0; j < 4; ++j) {
            int m = (lane >> 4) * 4 + j;
            out[(size_t)(n0 + m) * 256 + d] = acc[ct][j] + bv;
        }
    }
}

// ---------------------------------------------------------------------------
extern "C" void kernel_launch(void* const* d_in, const int* in_sizes, int n_in,
                              void* d_out, int out_size, void* d_ws, size_t ws_size,
                              hipStream_t stream)
{
    const float* op_feat  = (const float*)d_in[0];
    const float* mach_feat= (const float*)d_in[1];
    const float* tmask    = (const float*)d_in[2];
    const float* smask    = (const float*)d_in[3];
    const float* oma_q_w  = (const float*)d_in[4];
    const float* oma_q_b  = (const float*)d_in[5];
    const float* oma_kv_w = (const float*)d_in[6];
    const float* oma_kv_b = (const float*)d_in[7];
    const float* oma_s_w  = (const float*)d_in[8];
    const float* oma_s_b  = (const float*)d_in[9];
    const float* oma_o_w  = (const float*)d_in[10];
    const float* oma_o_b  = (const float*)d_in[11];
    const float* sa_w_w   = (const float*)d_in[12];
    const float* sa_w_b   = (const float*)d_in[13];
    const float* sa_s_w   = (const float*)d_in[14];
    const float* sa_s_b   = (const float*)d_in[15];
    const float* sa_o_w   = (const float*)d_in[16];
    const float* sa_o_b   = (const float*)d_in[17];
    const float* mix_w    = (const float*)d_in[18];
    const float* mix_b    = (const float*)d_in[19];

    char* ws = (char*)d_ws;
    float* wq_v   = (float*)(ws + 0);
    float* wk_v   = (float*)(ws + 1024);
    float* wq2_v  = (float*)(ws + 2048);
    float* wk2_v  = (float*)(ws + 3072);
    float* sb     = (float*)(ws + 4096);
    float* btot   = (float*)(ws + 4352);
    float* sqp    = (float*)(ws + 8192);
    float* skv    = (float*)(ws + 73728);
    float* sq2p   = (float*)(ws + 139264);
    float* sk2v   = (float*)(ws + 204800);
    __bf16* Wcat  = (__bf16*)(ws + 270336);    //  256 KB
    __bf16* vt    = (__bf16*)(ws + 532480);    //   16 MB : [2][8][256][2048]
    __bf16* wfcat = (__bf16*)(ws + 17309696);  //   16 MB : [16384][512]
    float* outp   = (float*)d_out;

    float* partial = (float*)(ws + 532480);    // 32 KB, overwritten by k3 later
    __bf16* opb   = (__bf16*)(ws + 17309696);            // 8 MB (dead until k4)
    __bf16* machb = (__bf16*)(ws + 17309696 + 8388608);  // 8 MB (dead until k4)

    k0a_partial<<<32, 256, 0, stream>>>(oma_q_w, oma_kv_w, sa_w_w,
                                        oma_s_w, sa_s_w, partial);
    k0b_reduce<<<1, 256, 0, stream>>>(partial, oma_q_b, oma_kv_b, oma_s_w, oma_s_b,
                                      sa_w_b, sa_s_w, sa_s_b,
                                      wq_v, wk_v, wq2_v, wk2_v, sb);
    k1_wcat<<<512, 256, 0, stream>>>(mix_w, mix_b, oma_o_w, oma_o_b,
                                     sa_o_w, sa_o_b, Wcat, btot);
    k2_scores<<<4096, 256, 0, stream>>>(op_feat, mach_feat, wq_v, wk_v, wq2_v, wk2_v,
                                        sb, sqp, skv, sq2p, sk2v, opb, machb);
    k3_vgemm<<<2048, 256, 0, stream>>>(opb, machb, oma_kv_w, sa_w_w, vt);
    k4_attn<<<512, 256, 0, stream>>>(tmask, smask, sqp, skv, sq2p, sk2v, vt, wfcat);
    k5_out<<<1024, 256, 0, stream>>>(wfcat, Wcat, btot, outp);
}